// Round 5
// baseline (575.954 us; speedup 1.0000x reference)
//
#include <hip/hip_runtime.h>

#define NSTEP 10
#define EPS32 5.9604645e-8f

// Load one 16-float image row as 4x float4.
__device__ __forceinline__ void load_row(const float* __restrict__ p, float* r) {
    const float4* q = reinterpret_cast<const float4*>(p);
    float4 a = q[0], b = q[1], c = q[2], d = q[3];
    r[0]=a.x;  r[1]=a.y;  r[2]=a.z;  r[3]=a.w;
    r[4]=b.x;  r[5]=b.y;  r[6]=b.z;  r[7]=b.w;
    r[8]=c.x;  r[9]=c.y;  r[10]=c.z; r[11]=c.w;
    r[12]=d.x; r[13]=d.y; r[14]=d.z; r[15]=d.w;
}

// Fused SNN forward. f32 fast path for conv+LIF1 with a SOUND rounding-error
// bound; any element whose spike margin is below the bound is redone in f64
// (rare) and the f64 FC accumulators are patched. FC accumulation stays f64
// (proven to match the np reference exactly in round 4).
// 8 threads per sample, one conv channel (256 elements) each.
__global__ __launch_bounds__(256) void snn_fused_fast(
    const float* __restrict__ x,       // [B,1,16,16]
    const float* __restrict__ conv_w,  // [8,1,3,3]
    const float* __restrict__ conv_b,  // [8]
    const float* __restrict__ fc_w,    // [2,2048]
    const float* __restrict__ fc_b,    // [2]
    float* __restrict__ out,           // [B,2]
    int B)
{
    // fc weights as double2 {w0_j, w1_j}, channel-padded to 257 so the 8
    // channel addresses hit disjoint 4-bank groups (conflict-free b128 reads;
    // same-address across samples is a free broadcast).
    __shared__ double2 fcwd[8 * 257];
    for (int j = threadIdx.x; j < 2048; j += 256) {
        const int c8 = j >> 8, idx = j & 255;
        fcwd[c8 * 257 + idx] = make_double2((double)fc_w[j], (double)fc_w[2048 + j]);
    }
    __syncthreads();

    const int g  = blockIdx.x * 256 + threadIdx.x;
    const int b  = g >> 3;
    const int ch = g & 7;
    if (b >= B) return;

    float cw[9], aw[9];
    #pragma unroll
    for (int k = 0; k < 9; ++k) { cw[k] = conv_w[ch * 9 + k]; aw[k] = fabsf(cw[k]); }
    const float cb = conv_b[ch];

    const float* xb = x + (size_t)b * 256;
    const double2* fcw_ch = &fcwd[ch * 257];

    double sx[NSTEP], sy[NSTEP];
    #pragma unroll
    for (int t = 0; t < NSTEP; ++t) { sx[t] = 0.0; sy[t] = 0.0; }

    // Sliding 3-row window (zero rows at boundaries; elided taps are exact
    // no-ops, so a zero-padded replica is bit-identical).
    float r0[16], r1[16], r2[16];
    #pragma unroll
    for (int k = 0; k < 16; ++k) r0[k] = 0.f;
    load_row(xb, r1);
    load_row(xb + 16, r2);

    for (int y = 0; y < 16; ++y) {
        unsigned rowflag = 0;
        #pragma unroll
        for (int xx = 0; xx < 16; ++xx) {
            // f32 conv + running abs-sum (error-bound input; abs folds to modifiers)
            float cf = cb;
            float sa = fabsf(cb);
            if (xx > 0) {
                cf = fmaf(cw[0], r0[xx-1], cf); sa = fmaf(aw[0], fabsf(r0[xx-1]), sa);
                cf = fmaf(cw[3], r1[xx-1], cf); sa = fmaf(aw[3], fabsf(r1[xx-1]), sa);
                cf = fmaf(cw[6], r2[xx-1], cf); sa = fmaf(aw[6], fabsf(r2[xx-1]), sa);
            }
            cf = fmaf(cw[1], r0[xx], cf); sa = fmaf(aw[1], fabsf(r0[xx]), sa);
            cf = fmaf(cw[4], r1[xx], cf); sa = fmaf(aw[4], fabsf(r1[xx]), sa);
            cf = fmaf(cw[7], r2[xx], cf); sa = fmaf(aw[7], fabsf(r2[xx]), sa);
            if (xx < 15) {
                cf = fmaf(cw[2], r0[xx+1], cf); sa = fmaf(aw[2], fabsf(r0[xx+1]), sa);
                cf = fmaf(cw[5], r1[xx+1], cf); sa = fmaf(aw[5], fabsf(r1[xx+1]), sa);
                cf = fmaf(cw[8], r2[xx+1], cf); sa = fmaf(aw[8], fabsf(r2[xx+1]), sa);
            }
            const double2 wd = fcw_ch[y * 16 + xx];
            const float cm1f = cf - 1.0f;
            // sound margin: 10*(16 eps sa) conv + 110 eps A recurrence (+slack)
            const float Am    = fmaxf(fabsf(cf), fabsf(cm1f));
            const float delta = fmaf(9.5367432e-6f, sa, fmaf(7.6293945e-6f, Am, 9.5367432e-7f));

            float memf = 0.f, mn = 1e30f;
            bool spk = false;
            #pragma unroll
            for (int t = 0; t < NSTEP; ++t) {
                memf = fmaf(0.9f, memf, spk ? cm1f : cf);
                const float sd = memf - 1.0f;
                spk = sd > 0.0f;
                mn = fminf(mn, fabsf(sd));
                const double spkd = spk ? 1.0 : 0.0;
                sx[t] = fma(spkd, wd.x, sx[t]);
                sy[t] = fma(spkd, wd.y, sy[t]);
            }
            if (mn < delta) rowflag |= (1u << xx);
        }

        // Rare exact redo: replicate f32 chain bit-exactly, compute f64 chain,
        // patch accumulators where spike bits differ.
        if (__builtin_expect(rowflag != 0, 0)) {
            while (rowflag) {
                const int xx = __builtin_ctz(rowflag);
                rowflag &= rowflag - 1;
                // reload 3x3 patch from global (zero-padded)
                float v[3][3];
                #pragma unroll
                for (int ky = 0; ky < 3; ++ky) {
                    const int ry = y + ky - 1;
                    #pragma unroll
                    for (int kx = 0; kx < 3; ++kx) {
                        const int rx = xx + kx - 1;
                        v[ky][kx] = (ry >= 0 && ry < 16 && rx >= 0 && rx < 16)
                                        ? xb[ry * 16 + rx] : 0.f;
                    }
                }
                // f32 replica (same op order; zero taps are exact no-ops)
                float cf = cb;
                cf = fmaf(cw[0], v[0][0], cf); cf = fmaf(cw[3], v[1][0], cf); cf = fmaf(cw[6], v[2][0], cf);
                cf = fmaf(cw[1], v[0][1], cf); cf = fmaf(cw[4], v[1][1], cf); cf = fmaf(cw[7], v[2][1], cf);
                cf = fmaf(cw[2], v[0][2], cf); cf = fmaf(cw[5], v[1][2], cf); cf = fmaf(cw[8], v[2][2], cf);
                const float cm1f = cf - 1.0f;
                unsigned b32 = 0;
                {
                    float memf = 0.f; bool spk = false;
                    #pragma unroll
                    for (int t = 0; t < NSTEP; ++t) {
                        memf = fmaf(0.9f, memf, spk ? cm1f : cf);
                        spk = (memf - 1.0f) > 0.0f;
                        b32 |= (unsigned)spk << t;
                    }
                }
                // f64 exact chain
                double c64 = (double)cb;
                c64 = fma((double)cw[0], (double)v[0][0], c64);
                c64 = fma((double)cw[3], (double)v[1][0], c64);
                c64 = fma((double)cw[6], (double)v[2][0], c64);
                c64 = fma((double)cw[1], (double)v[0][1], c64);
                c64 = fma((double)cw[4], (double)v[1][1], c64);
                c64 = fma((double)cw[7], (double)v[2][1], c64);
                c64 = fma((double)cw[2], (double)v[0][2], c64);
                c64 = fma((double)cw[5], (double)v[1][2], c64);
                c64 = fma((double)cw[8], (double)v[2][2], c64);
                const double cm164 = c64 - 1.0;
                unsigned b64m = 0;
                {
                    double mem = 0.0; bool sk = false;
                    #pragma unroll
                    for (int t = 0; t < NSTEP; ++t) {
                        mem = fma(0.9, mem, sk ? cm164 : c64);
                        sk = mem > 1.0;
                        b64m |= (unsigned)sk << t;
                    }
                }
                if (b64m != b32) {
                    const double2 wd = fcw_ch[y * 16 + xx];
                    #pragma unroll
                    for (int t = 0; t < NSTEP; ++t) {
                        const int d = (int)((b64m >> t) & 1u) - (int)((b32 >> t) & 1u);
                        if (d != 0) {
                            const double dd = (double)d;
                            sx[t] = fma(dd, wd.x, sx[t]);
                            sy[t] = fma(dd, wd.y, sy[t]);
                        }
                    }
                }
            }
        }

        // Slide the row window.
        #pragma unroll
        for (int k = 0; k < 16; ++k) { r0[k] = r1[k]; r1[k] = r2[k]; }
        if (y < 14) {
            load_row(xb + (y + 2) * 16, r2);
        } else {
            #pragma unroll
            for (int k = 0; k < 16; ++k) r2[k] = 0.f;
        }
    }

    // Combine the 8 per-channel partials of this sample.
    #pragma unroll
    for (int t = 0; t < NSTEP; ++t) {
        sx[t] += __shfl_xor(sx[t], 1);
        sy[t] += __shfl_xor(sy[t], 1);
        sx[t] += __shfl_xor(sx[t], 2);
        sy[t] += __shfl_xor(sy[t], 2);
        sx[t] += __shfl_xor(sx[t], 4);
        sy[t] += __shfl_xor(sy[t], 4);
    }

    if (ch == 0) {
        const double fb0 = (double)fc_b[0];
        const double fb1 = (double)fc_b[1];
        double m0 = 0.0, m1 = 0.0, p0 = 0.0, p1 = 0.0;
        float a0 = 0.f, a1 = 0.f;
        #pragma unroll
        for (int t = 0; t < NSTEP; ++t) {
            m0 = fma(0.9, m0, (sx[t] + fb0) - p0);
            m1 = fma(0.9, m1, (sy[t] + fb1) - p1);
            p0 = (m0 > 1.0) ? 1.0 : 0.0;
            p1 = (m1 > 1.0) ? 1.0 : 0.0;
            a0 += (float)p0;
            a1 += (float)p1;
        }
        reinterpret_cast<float2*>(out)[b] = make_float2(a0, a1);
    }
}

extern "C" void kernel_launch(void* const* d_in, const int* in_sizes, int n_in,
                              void* d_out, int out_size, void* d_ws, size_t ws_size,
                              hipStream_t stream) {
    const float* x      = (const float*)d_in[0];
    const float* conv_w = (const float*)d_in[1];
    const float* conv_b = (const float*)d_in[2];
    const float* fc_w   = (const float*)d_in[3];
    const float* fc_b   = (const float*)d_in[4];
    float* out = (float*)d_out;

    const int B = in_sizes[0] / 256;      // x is [B,1,16,16]
    const int threads = B * 8;            // 8 threads per sample (1 channel each)
    const int blocks = (threads + 255) / 256;
    snn_fused_fast<<<blocks, 256, 0, stream>>>(x, conv_w, conv_b, fc_w, fc_b, out, B);
}

// Round 8
// 412.898 us; speedup vs baseline: 1.3949x; 1.3949x over previous
//
#include <hip/hip_runtime.h>

#define NSTEP 10
#define MTHR 1.0e-3    // mem2 margin threshold -> full-f64 sample redo

__device__ __forceinline__ void load_row16(const float* __restrict__ p, float* r) {
    const float4* q = reinterpret_cast<const float4*>(p);
    float4 a = q[0], b = q[1], c = q[2], d = q[3];
    r[0]=a.x;  r[1]=a.y;  r[2]=a.z;  r[3]=a.w;
    r[4]=b.x;  r[5]=b.y;  r[6]=b.z;  r[7]=b.w;
    r[8]=c.x;  r[9]=c.y;  r[10]=c.z; r[11]=c.w;
    r[12]=d.x; r[13]=d.y; r[14]=d.z; r[15]=d.w;
}

__global__ void zero_counter(int* counter) {
    if (threadIdx.x == 0) counter[0] = 0;
}

// Main kernel: f32 conv + f32 LIF1 in u-form (u = mem-1, u0 = -1 !) with a
// sound margin bound and exact-f64 patch for borderline spikes; f32 FC
// accumulation; f64 LIF2 at lane0 with MTHR margin -> compacted full-f64 redo.
// 8 threads/sample, 1 conv channel each.
__global__ __launch_bounds__(256) void snn_main(
    const float* __restrict__ x,       // [B,1,16,16]
    const float* __restrict__ conv_w,  // [8,1,3,3]
    const float* __restrict__ conv_b,  // [8]
    const float* __restrict__ fc_w,    // [2,2048]
    const float* __restrict__ fc_b,    // [2]
    float* __restrict__ out,           // [B,2]
    int* __restrict__ counter,
    int* __restrict__ ids,
    int capacity,
    int B)
{
    __shared__ float2 fcw[8 * 257];    // 257-pad: conflict-free (r5-proven)
    for (int j = threadIdx.x; j < 2048; j += 256)
        fcw[(j >> 8) * 257 + (j & 255)] = make_float2(fc_w[j], fc_w[2048 + j]);
    __syncthreads();

    const int g  = blockIdx.x * 256 + threadIdx.x;
    const int b  = g >> 3;
    const int ch = g & 7;
    if (b >= B) return;

    float cw[9];
    #pragma unroll
    for (int k = 0; k < 9; ++k) cw[k] = conv_w[ch * 9 + k];
    const float cb = conv_b[ch];

    const float* xb = x + (size_t)b * 256;
    const float2* fcw_ch = &fcw[ch * 257];

    float sx[NSTEP], sy[NSTEP];
    #pragma unroll
    for (int t = 0; t < NSTEP; ++t) { sx[t] = 0.f; sy[t] = 0.f; }

    // 18-wide zero-padded sliding rows; tap (ky,kx) for out col xx = r{ky}[xx+kx].
    float r0[18], r1[18], r2[18];
    #pragma unroll
    for (int k = 0; k < 18; ++k) { r0[k] = 0.f; r1[k] = 0.f; r2[k] = 0.f; }
    load_row16(xb, &r1[1]);
    load_row16(xb + 16, &r2[1]);

    for (int y = 0; y < 16; ++y) {
        unsigned rowflag = 0;
        #pragma unroll 4
        for (int xx = 0; xx < 16; ++xx) {
            float cf = cb, sa = fabsf(cb);
            cf = fmaf(cw[0], r0[xx],   cf); sa = fmaf(fabsf(cw[0]), fabsf(r0[xx]),   sa);
            cf = fmaf(cw[3], r1[xx],   cf); sa = fmaf(fabsf(cw[3]), fabsf(r1[xx]),   sa);
            cf = fmaf(cw[6], r2[xx],   cf); sa = fmaf(fabsf(cw[6]), fabsf(r2[xx]),   sa);
            cf = fmaf(cw[1], r0[xx+1], cf); sa = fmaf(fabsf(cw[1]), fabsf(r0[xx+1]), sa);
            cf = fmaf(cw[4], r1[xx+1], cf); sa = fmaf(fabsf(cw[4]), fabsf(r1[xx+1]), sa);
            cf = fmaf(cw[7], r2[xx+1], cf); sa = fmaf(fabsf(cw[7]), fabsf(r2[xx+1]), sa);
            cf = fmaf(cw[2], r0[xx+2], cf); sa = fmaf(fabsf(cw[2]), fabsf(r0[xx+2]), sa);
            cf = fmaf(cw[5], r1[xx+2], cf); sa = fmaf(fabsf(cw[5]), fabsf(r1[xx+2]), sa);
            cf = fmaf(cw[8], r2[xx+2], cf); sa = fmaf(fabsf(cw[8]), fabsf(r2[xx+2]), sa);

            // u-form LIF1: u = mem-1, u0 = mem0-1 = -1 (r7 bug: was 0).
            const float c01 = cf - 0.1f;
            const float c11 = cf - 1.1f;
            const float Am  = fmaxf(fabsf(c01), fabsf(c11));
            const float delta = fmaf(1.4305115e-5f, sa, fmaf(1.1444092e-5f, Am, 3.0e-6f));

            const float2 w01 = fcw_ch[y * 16 + xx];
            float u = -1.0f, mn = 1e30f;
            bool spk = false;
            #pragma unroll
            for (int t = 0; t < NSTEP; ++t) {
                u = fmaf(0.9f, u, spk ? c11 : c01);
                spk = u > 0.0f;
                mn = fminf(mn, fabsf(u));
                const float spkf = spk ? 1.f : 0.f;
                sx[t] = fmaf(spkf, w01.x, sx[t]);
                sy[t] = fmaf(spkf, w01.y, sy[t]);
            }
            if (mn < delta) rowflag |= (1u << xx);
        }

        // Rare exact patch: bit-exact f32 replica vs f64 truth; fix accum diffs.
        if (__builtin_expect(rowflag != 0, 0)) {
            while (rowflag) {
                const int xx = __builtin_ctz(rowflag);
                rowflag &= rowflag - 1;
                float v[3][3];
                #pragma unroll
                for (int ky = 0; ky < 3; ++ky) {
                    const int ry = y + ky - 1;
                    #pragma unroll
                    for (int kx = 0; kx < 3; ++kx) {
                        const int rx = xx + kx - 1;
                        v[ky][kx] = (ry >= 0 && ry < 16 && rx >= 0 && rx < 16)
                                        ? xb[ry * 16 + rx] : 0.f;
                    }
                }
                // f32 replica, same tap order (zero taps are exact no-ops)
                float cf = cb;
                cf = fmaf(cw[0], v[0][0], cf); cf = fmaf(cw[3], v[1][0], cf); cf = fmaf(cw[6], v[2][0], cf);
                cf = fmaf(cw[1], v[0][1], cf); cf = fmaf(cw[4], v[1][1], cf); cf = fmaf(cw[7], v[2][1], cf);
                cf = fmaf(cw[2], v[0][2], cf); cf = fmaf(cw[5], v[1][2], cf); cf = fmaf(cw[8], v[2][2], cf);
                const float c01 = cf - 0.1f, c11 = cf - 1.1f;
                unsigned b32m = 0;
                {
                    float u = -1.0f; bool spk = false;     // matches fast path
                    #pragma unroll
                    for (int t = 0; t < NSTEP; ++t) {
                        u = fmaf(0.9f, u, spk ? c11 : c01);
                        spk = u > 0.0f;
                        b32m |= (unsigned)spk << t;
                    }
                }
                // f64 truth chain (mem-form, mem0=0, f64 0.9 — r4-proven)
                double c64 = (double)cb;
                c64 = fma((double)cw[0], (double)v[0][0], c64);
                c64 = fma((double)cw[3], (double)v[1][0], c64);
                c64 = fma((double)cw[6], (double)v[2][0], c64);
                c64 = fma((double)cw[1], (double)v[0][1], c64);
                c64 = fma((double)cw[4], (double)v[1][1], c64);
                c64 = fma((double)cw[7], (double)v[2][1], c64);
                c64 = fma((double)cw[2], (double)v[0][2], c64);
                c64 = fma((double)cw[5], (double)v[1][2], c64);
                c64 = fma((double)cw[8], (double)v[2][2], c64);
                const double cm1 = c64 - 1.0;
                unsigned b64m = 0;
                {
                    double mem = 0.0; bool spk = false;
                    #pragma unroll
                    for (int t = 0; t < NSTEP; ++t) {
                        mem = fma(0.9, mem, spk ? cm1 : c64);
                        spk = mem > 1.0;
                        b64m |= (unsigned)spk << t;
                    }
                }
                if (b64m != b32m) {
                    const float2 wd = fcw_ch[y * 16 + xx];
                    #pragma unroll
                    for (int t = 0; t < NSTEP; ++t) {
                        const int d = (int)((b64m >> t) & 1u) - (int)((b32m >> t) & 1u);
                        if (d != 0) {
                            sx[t] = fmaf((float)d, wd.x, sx[t]);
                            sy[t] = fmaf((float)d, wd.y, sy[t]);
                        }
                    }
                }
            }
        }

        // Slide window.
        #pragma unroll
        for (int k = 1; k < 17; ++k) { r0[k] = r1[k]; r1[k] = r2[k]; }
        if (y < 14) {
            load_row16(xb + (y + 2) * 16, &r2[1]);
        } else {
            #pragma unroll
            for (int k = 1; k < 17; ++k) r2[k] = 0.f;
        }
    }

    // Combine 8 per-channel f32 partials.
    #pragma unroll
    for (int t = 0; t < NSTEP; ++t) {
        sx[t] += __shfl_xor(sx[t], 1);
        sy[t] += __shfl_xor(sy[t], 1);
        sx[t] += __shfl_xor(sx[t], 2);
        sy[t] += __shfl_xor(sy[t], 2);
        sx[t] += __shfl_xor(sx[t], 4);
        sy[t] += __shfl_xor(sy[t], 4);
    }

    if (ch == 0) {
        const double fb0 = (double)fc_b[0];
        const double fb1 = (double)fc_b[1];
        double m0 = 0.0, m1 = 0.0, p0 = 0.0, p1 = 0.0, mn2 = 1e30;
        float a0 = 0.f, a1 = 0.f;
        #pragma unroll
        for (int t = 0; t < NSTEP; ++t) {
            m0 = fma(0.9, m0, ((double)sx[t] + fb0) - p0);
            m1 = fma(0.9, m1, ((double)sy[t] + fb1) - p1);
            mn2 = fmin(mn2, fabs(m0 - 1.0));
            mn2 = fmin(mn2, fabs(m1 - 1.0));
            p0 = (m0 > 1.0) ? 1.0 : 0.0;
            p1 = (m1 > 1.0) ? 1.0 : 0.0;
            a0 += (float)p0;
            a1 += (float)p1;
        }
        reinterpret_cast<float2*>(out)[b] = make_float2(a0, a1);
        if (mn2 < MTHR) {                 // borderline mem2 -> full f64 redo
            const int idx = atomicAdd(counter, 1);
            if (idx < capacity) ids[idx] = b;   // overflow -> redo-all fallback
        }
    }
}

// Full-f64 redo for flagged samples (round-4 code, proven absmax==0).
// If the id list overflowed capacity, redo ALL samples (safe fallback).
__global__ __launch_bounds__(256) void snn_redo(
    const float* __restrict__ x,
    const float* __restrict__ conv_w,
    const float* __restrict__ conv_b,
    const float* __restrict__ fc_w,
    const float* __restrict__ fc_b,
    float* __restrict__ out,
    const int* __restrict__ counter,
    const int* __restrict__ ids,
    int capacity,
    int B)
{
    __shared__ double2 fcwd[8 * 257];
    for (int j = threadIdx.x; j < 2048; j += 256)
        fcwd[(j >> 8) * 257 + (j & 255)] =
            make_double2((double)fc_w[j], (double)fc_w[2048 + j]);
    __syncthreads();

    const int g   = blockIdx.x * 256 + threadIdx.x;
    const int grp = g >> 3;
    const int ch  = g & 7;
    const int n   = counter[0];
    const bool all = (n > capacity);
    const int m = all ? B : n;
    if (grp >= m) return;
    const int b = all ? grp : ids[grp];

    double cw[9];
    #pragma unroll
    for (int k = 0; k < 9; ++k) cw[k] = (double)conv_w[ch * 9 + k];
    const double cb = (double)conv_b[ch];
    const float* xb = x + (size_t)b * 256;
    const double2* fcw_ch = &fcwd[ch * 257];

    double sx[NSTEP], sy[NSTEP];
    #pragma unroll
    for (int t = 0; t < NSTEP; ++t) { sx[t] = 0.0; sy[t] = 0.0; }

    float r0[18], r1[18], r2[18];
    #pragma unroll
    for (int k = 0; k < 18; ++k) { r0[k] = 0.f; r1[k] = 0.f; r2[k] = 0.f; }
    load_row16(xb, &r1[1]);
    load_row16(xb + 16, &r2[1]);

    for (int y = 0; y < 16; ++y) {
        #pragma unroll 4
        for (int xx = 0; xx < 16; ++xx) {
            double c = cb;
            c = fma(cw[0], (double)r0[xx],   c);
            c = fma(cw[3], (double)r1[xx],   c);
            c = fma(cw[6], (double)r2[xx],   c);
            c = fma(cw[1], (double)r0[xx+1], c);
            c = fma(cw[4], (double)r1[xx+1], c);
            c = fma(cw[7], (double)r2[xx+1], c);
            c = fma(cw[2], (double)r0[xx+2], c);
            c = fma(cw[5], (double)r1[xx+2], c);
            c = fma(cw[8], (double)r2[xx+2], c);
            const double2 wd = fcw_ch[y * 16 + xx];
            const double cm1 = c - 1.0;
            double mem = 0.0;
            bool spk = false;
            #pragma unroll
            for (int t = 0; t < NSTEP; ++t) {
                mem = fma(0.9, mem, spk ? cm1 : c);
                spk = mem > 1.0;
                sx[t] += spk ? wd.x : 0.0;
                sy[t] += spk ? wd.y : 0.0;
            }
        }
        #pragma unroll
        for (int k = 1; k < 17; ++k) { r0[k] = r1[k]; r1[k] = r2[k]; }
        if (y < 14) {
            load_row16(xb + (y + 2) * 16, &r2[1]);
        } else {
            #pragma unroll
            for (int k = 1; k < 17; ++k) r2[k] = 0.f;
        }
    }

    #pragma unroll
    for (int t = 0; t < NSTEP; ++t) {
        sx[t] += __shfl_xor(sx[t], 1);
        sy[t] += __shfl_xor(sy[t], 1);
        sx[t] += __shfl_xor(sx[t], 2);
        sy[t] += __shfl_xor(sy[t], 2);
        sx[t] += __shfl_xor(sx[t], 4);
        sy[t] += __shfl_xor(sy[t], 4);
    }

    if (ch == 0) {
        const double fb0 = (double)fc_b[0];
        const double fb1 = (double)fc_b[1];
        double m0 = 0.0, m1 = 0.0, p0 = 0.0, p1 = 0.0;
        float a0 = 0.f, a1 = 0.f;
        #pragma unroll
        for (int t = 0; t < NSTEP; ++t) {
            m0 = fma(0.9, m0, (sx[t] + fb0) - p0);
            m1 = fma(0.9, m1, (sy[t] + fb1) - p1);
            p0 = (m0 > 1.0) ? 1.0 : 0.0;
            p1 = (m1 > 1.0) ? 1.0 : 0.0;
            a0 += (float)p0;
            a1 += (float)p1;
        }
        reinterpret_cast<float2*>(out)[b] = make_float2(a0, a1);
    }
}

extern "C" void kernel_launch(void* const* d_in, const int* in_sizes, int n_in,
                              void* d_out, int out_size, void* d_ws, size_t ws_size,
                              hipStream_t stream) {
    const float* x      = (const float*)d_in[0];
    const float* conv_w = (const float*)d_in[1];
    const float* conv_b = (const float*)d_in[2];
    const float* fc_w   = (const float*)d_in[3];
    const float* fc_b   = (const float*)d_in[4];
    float* out = (float*)d_out;

    const int B = in_sizes[0] / 256;
    int* counter = (int*)d_ws;
    int* ids     = (int*)((char*)d_ws + 64);
    const int capacity = (int)((ws_size > 64 ? ws_size - 64 : 0) / sizeof(int));

    zero_counter<<<1, 64, 0, stream>>>(counter);
    const int blocks = (B * 8 + 255) / 256;
    snn_main<<<blocks, 256, 0, stream>>>(x, conv_w, conv_b, fc_w, fc_b, out,
                                         counter, ids, capacity, B);
    snn_redo<<<blocks, 256, 0, stream>>>(x, conv_w, conv_b, fc_w, fc_b, out,
                                         counter, ids, capacity, B);
}